// Round 12
// baseline (233.923 us; speedup 1.0000x reference)
//
#include <hip/hip_runtime.h>
#include <hip/hip_bf16.h>
#include <cfloat>

#define HD 128

typedef float f32x4 __attribute__((ext_vector_type(4)));
typedef __bf16 bf16x8 __attribute__((ext_vector_type(8)));

// -------- Kernel 1: segment bounds (batch is sorted) --------
__global__ void seg_bounds_kernel(const int* __restrict__ batch, int n, int nseg,
                                  int* __restrict__ seg_start) {
  int b = blockIdx.x * blockDim.x + threadIdx.x;
  if (b > nseg) return;
  if (b == nseg) { seg_start[b] = n; return; }
  int lo = 0, hi = n;
  while (lo < hi) {
    int mid = (lo + hi) >> 1;
    if (batch[mid] < b) lo = mid + 1; else hi = mid;
  }
  seg_start[b] = lo;
}

// 16-lane-row rotate (DPP) for the end-of-segment reduce.
template <int CTRL>
__device__ __forceinline__ float dpp_ror(float v) {
  return __int_as_float(__builtin_amdgcn_update_dpp(
      0, __float_as_int(v), CTRL, 0xF, 0xF, true));
}

// -------- Kernel 2: FUSED gate-score + FIXED-SHIFT softmax + pooling -------
// One wave per segment (static). Double-buffered h (hA/hB), branchless
// overrun-safe loop (clamped rows, w=0 masks).
// OPERAND-SWAPPED MFMA: D = W1^T (A-frag, same sWt reads) x H^T (B-frag,
// same h cvt) -> D[c][node] with node = lane&15 = the row this lane loaded.
// Every lane's 32 epilogue terms belong to ITS OWN node: score reduce is
// 3 in-lane adds + 2 shfl_xor (16,32) -- no DPP chain, no ds_bpermute.
// b1 is folded into the MFMA C-init; b1/w2 come from small LDS tables
// (broadcast b128 reads). gm-fmax hoisted before MFMA (overlaps).
// Score: score_shifted = -2 * sum(w2/(1+e^{2x})); consts cancel in softmax.

#define LOAD_TILE(BUF, T)                                                   \
  {                                                                         \
    const int nIt_ = (T) * 16 + lr;                                         \
    const size_t row_ = (size_t)s0 + (size_t)min(nIt_, lenm1);              \
    const float* hp_ = h + row_ * HD + 8 * kl;                              \
    _Pragma("unroll")                                                       \
    for (int kt = 0; kt < 4; ++kt) {                                        \
      *reinterpret_cast<float4*>(&BUF[8 * kt]) =                            \
          *reinterpret_cast<const float4*>(hp_ + 32 * kt);                  \
      *reinterpret_cast<float4*>(&BUF[8 * kt + 4]) =                        \
          *reinterpret_cast<const float4*>(hp_ + 32 * kt + 4);              \
    }                                                                       \
  }

#define PROC_TILE(BUF, T)                                                   \
  {                                                                         \
    const bool valid_ = ((T) * 16 + lr) < len;                              \
    bf16x8 a_[4];                                                           \
    _Pragma("unroll")                                                       \
    for (int kt = 0; kt < 4; ++kt)                                          \
      _Pragma("unroll")                                                     \
      for (int j = 0; j < 8; ++j) a_[kt][j] = (__bf16)BUF[8 * kt + j];      \
    /* early max-pool: overlaps under MFMA/trans, shortens post-w tail */   \
    _Pragma("unroll")                                                       \
    for (int j = 0; j < 32; ++j) gm[j] = fmaxf(gm[j], BUF[j]);              \
    /* opaque: keep LDS reads inside the loop (anti-LICM) */                \
    asm volatile("" : "+v"(Cb), "+v"(Tb));                                  \
    const char* tb_ = reinterpret_cast<const char*>(sTab) + Tb + 16 * kl;   \
    float p4_[4] = {0.f, 0.f, 0.f, 0.f};                                    \
    _Pragma("unroll")                                                       \
    for (int hf = 0; hf < 2; ++hf) {                                        \
      f32x4 macc_[4];                                                       \
      _Pragma("unroll")                                                     \
      for (int fh = 0; fh < 4; ++fh)  /* C-init = b1[c], folds the bias */  \
        macc_[fh] = *reinterpret_cast<const f32x4*>(                        \
            tb_ + 64 * (4 * hf + fh));                                      \
      __builtin_amdgcn_s_setprio(1);                                        \
      _Pragma("unroll")                                                     \
      for (int kt = 0; kt < 4; ++kt) {                                      \
        const char* bp_ = reinterpret_cast<const char*>(sWt) +              \
                          (Cb + ((kt ^ hi2) << 6)) + hf * 16384;            \
        bf16x8 bfr_[4];                                                     \
        _Pragma("unroll")                                                   \
        for (int fh = 0; fh < 4; ++fh)                                      \
          bfr_[fh] = *reinterpret_cast<const bf16x8*>(bp_ + fh * 4096);     \
        _Pragma("unroll")                                                   \
        for (int fh = 0; fh < 4; ++fh)  /* A = W1^T frag, B = h frag */     \
          macc_[fh] = __builtin_amdgcn_mfma_f32_16x16x32_bf16(              \
              bfr_[fh], a_[kt], macc_[fh], 0, 0, 0);                        \
      }                                                                     \
      __builtin_amdgcn_s_setprio(0);                                        \
      _Pragma("unroll")                                                     \
      for (int fh = 0; fh < 4; ++fh) {                                      \
        const f32x4 w2v_ = *reinterpret_cast<const f32x4*>(                 \
            tb_ + 512 + 64 * (4 * hf + fh));                                \
        _Pragma("unroll")                                                   \
        for (int r = 0; r < 4; ++r) {                                       \
          const float e_ = exp2f(LOG2E2 * macc_[fh][r]);                    \
          p4_[r] = fmaf(__builtin_amdgcn_rcpf(1.f + e_), w2v_[r], p4_[r]);  \
        }                                                                   \
      }                                                                     \
    }                                                                       \
    /* all 32 terms belong to node lr: in-lane + cross-kl reduce */         \
    float ps_ = (p4_[0] + p4_[1]) + (p4_[2] + p4_[3]);                      \
    ps_ += __shfl_xor(ps_, 16, 64);                                         \
    ps_ += __shfl_xor(ps_, 32, 64);                                         \
    const float w_ = valid_ ? exp2f(ps_ * NEG2LOG2E) : 0.f;                 \
    s += w_;                                                                \
    _Pragma("unroll")                                                       \
    for (int j = 0; j < 32; ++j) acc[j] = fmaf(BUF[j], w_, acc[j]);         \
  }

__global__ __launch_bounds__(256, 2) void fused_pool_kernel(
    const float* __restrict__ h, const float* __restrict__ w1,
    const float* __restrict__ b1, const float* __restrict__ w2,
    const int* __restrict__ seg_start, float* __restrict__ g, int B)
{
  __shared__ __bf16 sWt[HD * HD];  // W1^T bf16, XOR-swizzled 16B slots (32 KB)
  __shared__ float sTab[256];      // [0..128) = b1, [128..256) = w2

  for (int i = threadIdx.x; i < HD * HD / 4; i += 256) {
    const int k = i >> 5;
    const int c4 = (i & 31) << 2;
    const float4 v = reinterpret_cast<const float4*>(w1)[i];
    const float vv[4] = {v.x, v.y, v.z, v.w};
#pragma unroll
    for (int q = 0; q < 4; ++q) {
      const int c = c4 + q;
      sWt[c * HD + ((((k >> 3) ^ (c & 15)) << 3) | (k & 7))] = (__bf16)vv[q];
    }
  }
  sTab[threadIdx.x] = (threadIdx.x < 128) ? b1[threadIdx.x]
                                          : w2[threadIdx.x - 128];
  __syncthreads();

  const float LOG2E2    = 2.88539008177792681f;   // 2*log2(e)
  const float NEG2LOG2E = -2.88539008177792681f;  // -2*log2(e)

  const int lane = threadIdx.x & 63;
  const int wid  = threadIdx.x >> 6;
  const int lr   = lane & 15;
  const int kl   = lane >> 4;

  // B-fragment (W1^T) LDS byte offsets: addr = Cb + ((kt^hi2)<<6) +
  //   hf*16384 + fh*4096  (c & 15 == lr for every fragment column).
  const int hi2 = (lr >> 2) & 3;
  int Cb = lr * 256 + ((kl ^ (lr & 3)) << 4);
  int Tb = 0;   // opaque base for the b1/w2 tables (anti-LICM)

  const int segStride = gridDim.x * 4;
  for (int b = blockIdx.x * 4 + wid; b < B; b += segStride) {
    const int s0  = seg_start[b];
    const int len = seg_start[b + 1] - s0;
    const int lenm1 = len - 1;
    const int nt  = (len + 15) >> 4;

    float s = 0.f;
    float acc[32], gm[32];
#pragma unroll
    for (int j = 0; j < 32; ++j) { acc[j] = 0.f; gm[j] = -FLT_MAX; }

    if (nt > 0) {
      float hA[32], hB[32];
      LOAD_TILE(hA, 0)
      LOAD_TILE(hB, 1)
      for (int t = 0; t < nt; t += 2) {   // branchless; overruns are no-ops
        PROC_TILE(hA, t)
        LOAD_TILE(hA, t + 2)
        PROC_TILE(hB, t + 1)
        LOAD_TILE(hB, t + 3)
      }
    }

    // Final reduce across the 16 lr lanes (features depend only on kl).
#pragma unroll
    for (int st = 1; st <= 8; st <<= 1) {
      if (st == 1) {
        s += dpp_ror<0x121>(s);
#pragma unroll
        for (int j = 0; j < 32; ++j) {
          acc[j] += dpp_ror<0x121>(acc[j]);
          gm[j] = fmaxf(gm[j], dpp_ror<0x121>(gm[j]));
        }
      } else if (st == 2) {
        s += dpp_ror<0x122>(s);
#pragma unroll
        for (int j = 0; j < 32; ++j) {
          acc[j] += dpp_ror<0x122>(acc[j]);
          gm[j] = fmaxf(gm[j], dpp_ror<0x122>(gm[j]));
        }
      } else if (st == 4) {
        s += dpp_ror<0x124>(s);
#pragma unroll
        for (int j = 0; j < 32; ++j) {
          acc[j] += dpp_ror<0x124>(acc[j]);
          gm[j] = fmaxf(gm[j], dpp_ror<0x124>(gm[j]));
        }
      } else {
        s += dpp_ror<0x128>(s);
#pragma unroll
        for (int j = 0; j < 32; ++j) {
          acc[j] += dpp_ror<0x128>(acc[j]);
          gm[j] = fmaxf(gm[j], dpp_ror<0x128>(gm[j]));
        }
      }
    }

    if (lr == 0) {  // lanes 0,16,32,48: one per kl group
      const float invS = (s > 0.f) ? 1.f / s : 0.f;
#pragma unroll
      for (int kt = 0; kt < 4; ++kt) {
        const int fb = 32 * kt + 8 * kl;
        float4 va, vb, ma, mb;
        va.x = acc[8*kt+0]*invS; va.y = acc[8*kt+1]*invS;
        va.z = acc[8*kt+2]*invS; va.w = acc[8*kt+3]*invS;
        vb.x = acc[8*kt+4]*invS; vb.y = acc[8*kt+5]*invS;
        vb.z = acc[8*kt+6]*invS; vb.w = acc[8*kt+7]*invS;
        ma.x = gm[8*kt+0]; ma.y = gm[8*kt+1]; ma.z = gm[8*kt+2]; ma.w = gm[8*kt+3];
        mb.x = gm[8*kt+4]; mb.y = gm[8*kt+5]; mb.z = gm[8*kt+6]; mb.w = gm[8*kt+7];
        *reinterpret_cast<float4*>(&g[(size_t)b * 256 + fb])           = va;
        *reinterpret_cast<float4*>(&g[(size_t)b * 256 + fb + 4])       = vb;
        *reinterpret_cast<float4*>(&g[(size_t)b * 256 + 128 + fb])     = ma;
        *reinterpret_cast<float4*>(&g[(size_t)b * 256 + 128 + fb + 4]) = mb;
      }
    }
  }
}

// -------- Kernel 3: MLP head, 4 segments per block --------
__global__ __launch_bounds__(512) void mlp_kernel(
    const float* __restrict__ g, const float* __restrict__ w1,
    const float* __restrict__ b1, const float* __restrict__ w2,
    const float* __restrict__ b2, float* __restrict__ out)
{
  __shared__ float sg[4][256];
  __shared__ float sred[4][2];
  const int t = threadIdx.x;
  const int sidx = t >> 7;
  const int u = t & 127;
  const int b0 = blockIdx.x * 4;
  sg[sidx][u]       = g[(size_t)(b0 + sidx) * 256 + u];
  sg[sidx][u + 128] = g[(size_t)(b0 + sidx) * 256 + 128 + u];
  __syncthreads();
  float acc = b1[u];
#pragma unroll 8
  for (int k = 0; k < 256; ++k)
    acc = fmaf(sg[sidx][k], w1[k * HD + u], acc);
  float v = fmaxf(acc, 0.f) * w2[u];
#pragma unroll
  for (int off = 32; off >= 1; off >>= 1) v += __shfl_xor(v, off, 64);
  if ((t & 63) == 0) sred[sidx][(t >> 6) & 1] = v;
  __syncthreads();
  if (u == 0) out[b0 + sidx] = sred[sidx][0] + sred[sidx][1] + b2[0];
}

extern "C" void kernel_launch(void* const* d_in, const int* in_sizes, int n_in,
                              void* d_out, int out_size, void* d_ws, size_t ws_size,
                              hipStream_t stream) {
  const float* h       = (const float*)d_in[0];
  const int*   batch   = (const int*)d_in[1];
  const float* gate_w1 = (const float*)d_in[2];
  const float* gate_b1 = (const float*)d_in[3];
  const float* gate_w2 = (const float*)d_in[4];
  const float* mlp_w1  = (const float*)d_in[6];
  const float* mlp_b1  = (const float*)d_in[7];
  const float* mlp_w2  = (const float*)d_in[8];
  const float* mlp_b2  = (const float*)d_in[9];
  float* out = (float*)d_out;

  const int N = in_sizes[0] / HD;   // 1048576
  const int B = out_size;           // 4096

  char* ws = (char*)d_ws;
  float* g   = (float*)ws;                              // B*256 floats
  int*   seg = (int*)(ws + (size_t)B * 256 * 4);        // B+1 ints

  seg_bounds_kernel<<<(B + 256) / 256, 256, 0, stream>>>(batch, N, B, seg);
  // 1024 blocks x 4 waves = 4096 waves -> one segment per wave (static).
  fused_pool_kernel<<<1024, 256, 0, stream>>>(h, gate_w1, gate_b1, gate_w2,
                                              seg, g, B);
  mlp_kernel<<<B / 4, 512, 0, stream>>>(g, mlp_w1, mlp_b1, mlp_w2, mlp_b2, out);
}

// Round 13
// 179.671 us; speedup vs baseline: 1.3020x; 1.3020x over previous
//
#include <hip/hip_runtime.h>
#include <hip/hip_bf16.h>
#include <cfloat>

#define HD 128

typedef float f32x4 __attribute__((ext_vector_type(4)));
typedef __bf16 bf16x8 __attribute__((ext_vector_type(8)));

// -------- Kernel 1: segment bounds (batch is sorted) --------
__global__ void seg_bounds_kernel(const int* __restrict__ batch, int n, int nseg,
                                  int* __restrict__ seg_start) {
  int b = blockIdx.x * blockDim.x + threadIdx.x;
  if (b > nseg) return;
  if (b == nseg) { seg_start[b] = n; return; }
  int lo = 0, hi = n;
  while (lo < hi) {
    int mid = (lo + hi) >> 1;
    if (batch[mid] < b) lo = mid + 1; else hi = mid;
  }
  seg_start[b] = lo;
}

// 16-lane-row rotate (DPP) for reductions.
template <int CTRL>
__device__ __forceinline__ float dpp_ror(float v) {
  return __int_as_float(__builtin_amdgcn_update_dpp(
      0, __float_as_int(v), CTRL, 0xF, 0xF, true));
}

// -------- Kernel 2: FUSED gate-score + FIXED-SHIFT softmax + pooling -------
// One wave per segment (static, 4096 waves). Double-buffered h (hA/hB, 64
// regs — hard budget; every 96-reg triple-buffer attempt spilled).
// Branchless 2-deep loop (clamped-row overruns are no-ops: w=0).
// UN-HALVED macc (R10's halving was only for the failed triple buffer):
// one wide setprio bracket, 8 independent MFMA chains of depth 4, LDS
// B-fragments read in 8-wide bursts per kt. gm-fmax hoisted before MFMA
// so it issues under the MFMA/trans section. Constants (w2r/b1s) stay
// register-resident (R12 lesson: LDS tables put latency on the chain).
// Score: score = sumW2 - 2*sum(w2/(1+e^{2x})); consts cancel in softmax,
// |score - const| <= 2*sum|w2| ~ 11 -> fixed shift is fp32-safe.

#define LOAD_TILE(BUF, T)                                                   \
  {                                                                         \
    const int nIt_ = (T) * 16 + lr;                                         \
    const size_t row_ = (size_t)s0 + (size_t)min(nIt_, lenm1);              \
    const float* hp_ = h + row_ * HD + 8 * kl;                              \
    _Pragma("unroll")                                                       \
    for (int kt = 0; kt < 4; ++kt) {                                        \
      *reinterpret_cast<float4*>(&BUF[8 * kt]) =                            \
          *reinterpret_cast<const float4*>(hp_ + 32 * kt);                  \
      *reinterpret_cast<float4*>(&BUF[8 * kt + 4]) =                        \
          *reinterpret_cast<const float4*>(hp_ + 32 * kt + 4);              \
    }                                                                       \
  }

#define PROC_TILE(BUF, T)                                                   \
  {                                                                         \
    const bool valid_ = ((T) * 16 + lr) < len;                              \
    bf16x8 a_[4];                                                           \
    _Pragma("unroll")                                                       \
    for (int kt = 0; kt < 4; ++kt)                                          \
      _Pragma("unroll")                                                     \
      for (int j = 0; j < 8; ++j) a_[kt][j] = (__bf16)BUF[8 * kt + j];      \
    /* early max-pool: issues under the MFMA/trans section */               \
    _Pragma("unroll")                                                       \
    for (int j = 0; j < 32; ++j) gm[j] = fmaxf(gm[j], BUF[j]);              \
    /* opaque: keep B-frag reads inside the loop (anti-LICM) */             \
    asm volatile("" : "+v"(Cb));                                            \
    f32x4 macc_[8];                                                         \
    _Pragma("unroll")                                                       \
    for (int f = 0; f < 8; ++f) macc_[f] = (f32x4){0.f, 0.f, 0.f, 0.f};     \
    __builtin_amdgcn_s_setprio(1);                                          \
    _Pragma("unroll")                                                       \
    for (int kt = 0; kt < 4; ++kt) {                                        \
      const char* bp_ = reinterpret_cast<const char*>(sWt) +                \
                        (Cb + ((kt ^ hi2) << 6));                           \
      bf16x8 bfr_[8];                                                       \
      _Pragma("unroll")                                                     \
      for (int f = 0; f < 8; ++f)                                           \
        bfr_[f] = *reinterpret_cast<const bf16x8*>(bp_ + f * 4096);         \
      _Pragma("unroll")                                                     \
      for (int f = 0; f < 8; ++f)                                           \
        macc_[f] = __builtin_amdgcn_mfma_f32_16x16x32_bf16(                 \
            a_[kt], bfr_[f], macc_[f], 0, 0, 0);                            \
    }                                                                       \
    __builtin_amdgcn_s_setprio(0);                                          \
    float p2_[4] = {0.f, 0.f, 0.f, 0.f};                                    \
    _Pragma("unroll")                                                       \
    for (int f = 0; f < 8; ++f) {                                           \
      _Pragma("unroll")                                                     \
      for (int r = 0; r < 4; ++r) {                                         \
        const float xe_ = fmaf(LOG2E2, macc_[f][r], b1s[f]);                \
        const float e_ = exp2f(xe_);                                        \
        const float t_ = __builtin_amdgcn_rcpf(1.f + e_);                   \
        p2_[r] = fmaf(t_, w2r[f], p2_[r]);                                  \
      }                                                                     \
    }                                                                       \
    /* 16-lane row sum via DPP rotate-adds (1+2+4+8 covers 16) */           \
    _Pragma("unroll")                                                       \
    for (int r = 0; r < 4; ++r) {                                           \
      p2_[r] += dpp_ror<0x121>(p2_[r]);                                     \
      p2_[r] += dpp_ror<0x122>(p2_[r]);                                     \
      p2_[r] += dpp_ror<0x124>(p2_[r]);                                     \
      p2_[r] += dpp_ror<0x128>(p2_[r]);                                     \
    }                                                                       \
    const int rr_ = lr & 3;                                                 \
    const float psel_ =                                                     \
        rr_ == 0 ? p2_[0] : (rr_ == 1 ? p2_[1] : (rr_ == 2 ? p2_[2]         \
                                                            : p2_[3]));     \
    const float sc_ = __shfl(psel_, ((lr >> 2) << 4) | (lr & 3), 64);       \
    const float w_ = valid_ ? exp2f(sc_ * NEG2LOG2E) : 0.f;                 \
    s += w_;                                                                \
    _Pragma("unroll")                                                       \
    for (int j = 0; j < 32; ++j) acc[j] = fmaf(BUF[j], w_, acc[j]);         \
  }

__global__ __launch_bounds__(256, 2) void fused_pool_kernel(
    const float* __restrict__ h, const float* __restrict__ w1,
    const float* __restrict__ b1, const float* __restrict__ w2,
    const int* __restrict__ seg_start, float* __restrict__ g, int B)
{
  __shared__ __bf16 sWt[HD * HD];  // W1^T bf16, XOR-swizzled 16B slots (32 KB)

  for (int i = threadIdx.x; i < HD * HD / 4; i += 256) {
    const int k = i >> 5;
    const int c4 = (i & 31) << 2;
    const float4 v = reinterpret_cast<const float4*>(w1)[i];
    const float vv[4] = {v.x, v.y, v.z, v.w};
#pragma unroll
    for (int q = 0; q < 4; ++q) {
      const int c = c4 + q;
      sWt[c * HD + ((((k >> 3) ^ (c & 15)) << 3) | (k & 7))] = (__bf16)vv[q];
    }
  }
  __syncthreads();

  const float LOG2E2    = 2.88539008177792681f;   // 2*log2(e)
  const float NEG2LOG2E = -2.88539008177792681f;  // -2*log2(e)

  const int lane = threadIdx.x & 63;
  const int wid  = threadIdx.x >> 6;
  const int lr   = lane & 15;
  const int kl   = lane >> 4;

  float w2r[8], b1s[8];
#pragma unroll
  for (int f = 0; f < 8; ++f) {
    w2r[f] = w2[16 * f + lr];
    b1s[f] = LOG2E2 * b1[16 * f + lr];
  }

  // B-fragment LDS byte offsets: addr(kt,f) = Cb + ((kt^hi2)<<6) + f*4096
  // (c & 15 == lr for every fragment column c = 16f + lr.)
  const int hi2 = (lr >> 2) & 3;
  int Cb = lr * 256 + ((kl ^ (lr & 3)) << 4);

  const int segStride = gridDim.x * 4;
  for (int b = blockIdx.x * 4 + wid; b < B; b += segStride) {
    const int s0  = seg_start[b];
    const int len = seg_start[b + 1] - s0;
    const int lenm1 = len - 1;
    const int nt  = (len + 15) >> 4;

    float s = 0.f;
    float acc[32], gm[32];
#pragma unroll
    for (int j = 0; j < 32; ++j) { acc[j] = 0.f; gm[j] = -FLT_MAX; }

    if (nt > 0) {
      float hA[32], hB[32];
      LOAD_TILE(hA, 0)
      LOAD_TILE(hB, 1)
      for (int t = 0; t < nt; t += 2) {   // branchless; overruns are no-ops
        PROC_TILE(hA, t)
        LOAD_TILE(hA, t + 2)
        PROC_TILE(hB, t + 1)
        LOAD_TILE(hB, t + 3)
      }
    }

    // Final reduce across the 16 lr lanes, on the VALU (DPP rotate-ops).
#pragma unroll
    for (int st = 1; st <= 8; st <<= 1) {
      if (st == 1) {
        s += dpp_ror<0x121>(s);
#pragma unroll
        for (int j = 0; j < 32; ++j) {
          acc[j] += dpp_ror<0x121>(acc[j]);
          gm[j] = fmaxf(gm[j], dpp_ror<0x121>(gm[j]));
        }
      } else if (st == 2) {
        s += dpp_ror<0x122>(s);
#pragma unroll
        for (int j = 0; j < 32; ++j) {
          acc[j] += dpp_ror<0x122>(acc[j]);
          gm[j] = fmaxf(gm[j], dpp_ror<0x122>(gm[j]));
        }
      } else if (st == 4) {
        s += dpp_ror<0x124>(s);
#pragma unroll
        for (int j = 0; j < 32; ++j) {
          acc[j] += dpp_ror<0x124>(acc[j]);
          gm[j] = fmaxf(gm[j], dpp_ror<0x124>(gm[j]));
        }
      } else {
        s += dpp_ror<0x128>(s);
#pragma unroll
        for (int j = 0; j < 32; ++j) {
          acc[j] += dpp_ror<0x128>(acc[j]);
          gm[j] = fmaxf(gm[j], dpp_ror<0x128>(gm[j]));
        }
      }
    }

    if (lr == 0) {  // lanes 0,16,32,48: one per kl group
      const float invS = (s > 0.f) ? 1.f / s : 0.f;
#pragma unroll
      for (int kt = 0; kt < 4; ++kt) {
        const int fb = 32 * kt + 8 * kl;
        float4 va, vb, ma, mb;
        va.x = acc[8*kt+0]*invS; va.y = acc[8*kt+1]*invS;
        va.z = acc[8*kt+2]*invS; va.w = acc[8*kt+3]*invS;
        vb.x = acc[8*kt+4]*invS; vb.y = acc[8*kt+5]*invS;
        vb.z = acc[8*kt+6]*invS; vb.w = acc[8*kt+7]*invS;
        ma.x = gm[8*kt+0]; ma.y = gm[8*kt+1]; ma.z = gm[8*kt+2]; ma.w = gm[8*kt+3];
        mb.x = gm[8*kt+4]; mb.y = gm[8*kt+5]; mb.z = gm[8*kt+6]; mb.w = gm[8*kt+7];
        *reinterpret_cast<float4*>(&g[(size_t)b * 256 + fb])           = va;
        *reinterpret_cast<float4*>(&g[(size_t)b * 256 + fb + 4])       = vb;
        *reinterpret_cast<float4*>(&g[(size_t)b * 256 + 128 + fb])     = ma;
        *reinterpret_cast<float4*>(&g[(size_t)b * 256 + 128 + fb + 4]) = mb;
      }
    }
  }
}

// -------- Kernel 3: MLP head, 4 segments per block --------
__global__ __launch_bounds__(512) void mlp_kernel(
    const float* __restrict__ g, const float* __restrict__ w1,
    const float* __restrict__ b1, const float* __restrict__ w2,
    const float* __restrict__ b2, float* __restrict__ out)
{
  __shared__ float sg[4][256];
  __shared__ float sred[4][2];
  const int t = threadIdx.x;
  const int sidx = t >> 7;
  const int u = t & 127;
  const int b0 = blockIdx.x * 4;
  sg[sidx][u]       = g[(size_t)(b0 + sidx) * 256 + u];
  sg[sidx][u + 128] = g[(size_t)(b0 + sidx) * 256 + 128 + u];
  __syncthreads();
  float acc = b1[u];
#pragma unroll 8
  for (int k = 0; k < 256; ++k)
    acc = fmaf(sg[sidx][k], w1[k * HD + u], acc);
  float v = fmaxf(acc, 0.f) * w2[u];
#pragma unroll
  for (int off = 32; off >= 1; off >>= 1) v += __shfl_xor(v, off, 64);
  if ((t & 63) == 0) sred[sidx][(t >> 6) & 1] = v;
  __syncthreads();
  if (u == 0) out[b0 + sidx] = sred[sidx][0] + sred[sidx][1] + b2[0];
}

extern "C" void kernel_launch(void* const* d_in, const int* in_sizes, int n_in,
                              void* d_out, int out_size, void* d_ws, size_t ws_size,
                              hipStream_t stream) {
  const float* h       = (const float*)d_in[0];
  const int*   batch   = (const int*)d_in[1];
  const float* gate_w1 = (const float*)d_in[2];
  const float* gate_b1 = (const float*)d_in[3];
  const float* gate_w2 = (const float*)d_in[4];
  const float* mlp_w1  = (const float*)d_in[6];
  const float* mlp_b1  = (const float*)d_in[7];
  const float* mlp_w2  = (const float*)d_in[8];
  const float* mlp_b2  = (const float*)d_in[9];
  float* out = (float*)d_out;

  const int N = in_sizes[0] / HD;   // 1048576
  const int B = out_size;           // 4096

  char* ws = (char*)d_ws;
  float* g   = (float*)ws;                              // B*256 floats
  int*   seg = (int*)(ws + (size_t)B * 256 * 4);        // B+1 ints

  seg_bounds_kernel<<<(B + 256) / 256, 256, 0, stream>>>(batch, N, B, seg);
  // 1024 blocks x 4 waves = 4096 waves -> one segment per wave (static).
  fused_pool_kernel<<<1024, 256, 0, stream>>>(h, gate_w1, gate_b1, gate_w2,
                                              seg, g, B);
  mlp_kernel<<<B / 4, 512, 0, stream>>>(g, mlp_w1, mlp_b1, mlp_w2, mlp_b2, out);
}

// Round 14
// 165.517 us; speedup vs baseline: 1.4133x; 1.0855x over previous
//
#include <hip/hip_runtime.h>
#include <hip/hip_bf16.h>
#include <cfloat>

#define HD 128

typedef float f32x4 __attribute__((ext_vector_type(4)));
typedef __bf16 bf16x8 __attribute__((ext_vector_type(8)));

// -------- Kernel 1: segment bounds (batch is sorted) --------
__global__ void seg_bounds_kernel(const int* __restrict__ batch, int n, int nseg,
                                  int* __restrict__ seg_start) {
  int b = blockIdx.x * blockDim.x + threadIdx.x;
  if (b > nseg) return;
  if (b == nseg) { seg_start[b] = n; return; }
  int lo = 0, hi = n;
  while (lo < hi) {
    int mid = (lo + hi) >> 1;
    if (batch[mid] < b) lo = mid + 1; else hi = mid;
  }
  seg_start[b] = lo;
}

// 16-lane-row rotate (DPP): dst lane i gets lane (i+N) mod 16 within its row.
template <int CTRL>
__device__ __forceinline__ float dpp_ror(float v) {
  return __int_as_float(__builtin_amdgcn_update_dpp(
      0, __float_as_int(v), CTRL, 0xF, 0xF, true));
}

// -------- Kernel 2: FUSED gate-score + FIXED-SHIFT softmax + pooling -------
// The 164.5us structure (R10 proposal), verbatim, plus ONE change: gm-fmax
// hoisted before the MFMA section (issues on VALU under MFMA/ds_read instead
// of in the post-w_ serial tail).
// One wave per segment (static, 4096 waves). Double-buffered h (hA/hB, 64
// regs — hard budget). Branchless 2-deep loop (clamped rows; overrun PROCs
// are no-ops, w=0). macc HALVED in two 4-col-fragment halves: the trans
// epilogue of half 0 overlaps the MFMA burst of half 1 (separate pipes) —
// un-halving this cost +15us (R13). Per-kt transient cvt keeps regs low.
// Score: score = sumW2 - 2*sum(w2/(1+e^{2x})); consts cancel in softmax,
// |score - const| <= 2*sum|w2| ~ 11 -> fixed shift is fp32-safe.

#define LOAD_TILE(BUF, T)                                                   \
  {                                                                         \
    const int nIt_ = (T) * 16 + lr;                                         \
    const size_t row_ = (size_t)s0 + (size_t)min(nIt_, lenm1);              \
    const float* hp_ = h + row_ * HD + 8 * kl;                              \
    _Pragma("unroll")                                                       \
    for (int kt = 0; kt < 4; ++kt) {                                        \
      *reinterpret_cast<float4*>(&BUF[8 * kt]) =                            \
          *reinterpret_cast<const float4*>(hp_ + 32 * kt);                  \
      *reinterpret_cast<float4*>(&BUF[8 * kt + 4]) =                        \
          *reinterpret_cast<const float4*>(hp_ + 32 * kt + 4);              \
    }                                                                       \
  }

#define PROC_TILE(BUF, T)                                                   \
  {                                                                         \
    const bool valid_ = ((T) * 16 + lr) < len;                              \
    /* early max-pool: issues under the MFMA/ds_read section */             \
    _Pragma("unroll")                                                       \
    for (int j = 0; j < 32; ++j) gm[j] = fmaxf(gm[j], BUF[j]);              \
    /* opaque: keep B-frag reads inside the loop (anti-LICM) */             \
    asm volatile("" : "+v"(Cb));                                            \
    float p2_[4] = {0.f, 0.f, 0.f, 0.f};                                    \
    _Pragma("unroll")                                                       \
    for (int hf = 0; hf < 2; ++hf) {                                        \
      f32x4 macc_[4];                                                       \
      _Pragma("unroll")                                                     \
      for (int fh = 0; fh < 4; ++fh) macc_[fh] = (f32x4){0.f, 0.f, 0.f, 0.f}; \
      __builtin_amdgcn_s_setprio(1);                                        \
      _Pragma("unroll")                                                     \
      for (int kt = 0; kt < 4; ++kt) {                                      \
        bf16x8 acur_;                                                       \
        _Pragma("unroll")                                                   \
        for (int j = 0; j < 8; ++j) acur_[j] = (__bf16)BUF[8 * kt + j];     \
        const char* bp_ = reinterpret_cast<const char*>(sWt) +              \
                          (Cb + ((kt ^ hi2) << 6)) + hf * 16384;            \
        bf16x8 bfr_[4];                                                     \
        _Pragma("unroll")                                                   \
        for (int fh = 0; fh < 4; ++fh)                                      \
          bfr_[fh] = *reinterpret_cast<const bf16x8*>(bp_ + fh * 4096);     \
        _Pragma("unroll")                                                   \
        for (int fh = 0; fh < 4; ++fh)                                      \
          macc_[fh] = __builtin_amdgcn_mfma_f32_16x16x32_bf16(              \
              acur_, bfr_[fh], macc_[fh], 0, 0, 0);                         \
      }                                                                     \
      __builtin_amdgcn_s_setprio(0);                                        \
      _Pragma("unroll")                                                     \
      for (int fh = 0; fh < 4; ++fh) {                                      \
        const int f_ = 4 * hf + fh;                                         \
        _Pragma("unroll")                                                   \
        for (int r = 0; r < 4; ++r) {                                       \
          const float xe_ = fmaf(LOG2E2, macc_[fh][r], b1s[f_]);            \
          const float e_ = exp2f(xe_);                                      \
          const float t_ = __builtin_amdgcn_rcpf(1.f + e_);                 \
          p2_[r] = fmaf(t_, w2r[f_], p2_[r]);                               \
        }                                                                   \
      }                                                                     \
    }                                                                       \
    /* 16-lane row sum via DPP rotate-adds (1+2+4+8 covers 16) */           \
    _Pragma("unroll")                                                       \
    for (int r = 0; r < 4; ++r) {                                           \
      p2_[r] += dpp_ror<0x121>(p2_[r]);                                     \
      p2_[r] += dpp_ror<0x122>(p2_[r]);                                     \
      p2_[r] += dpp_ror<0x124>(p2_[r]);                                     \
      p2_[r] += dpp_ror<0x128>(p2_[r]);                                     \
    }                                                                       \
    const int rr_ = lr & 3;                                                 \
    const float psel_ =                                                     \
        rr_ == 0 ? p2_[0] : (rr_ == 1 ? p2_[1] : (rr_ == 2 ? p2_[2]         \
                                                            : p2_[3]));     \
    const float sc_ = __shfl(psel_, ((lr >> 2) << 4) | (lr & 3), 64);       \
    const float w_ = valid_ ? exp2f(sc_ * NEG2LOG2E) : 0.f;                 \
    s += w_;                                                                \
    _Pragma("unroll")                                                       \
    for (int j = 0; j < 32; ++j) acc[j] = fmaf(BUF[j], w_, acc[j]);         \
  }

__global__ __launch_bounds__(256, 2) void fused_pool_kernel(
    const float* __restrict__ h, const float* __restrict__ w1,
    const float* __restrict__ b1, const float* __restrict__ w2,
    const int* __restrict__ seg_start, float* __restrict__ g, int B)
{
  __shared__ __bf16 sWt[HD * HD];  // W1^T bf16, XOR-swizzled 16B slots (32 KB)

  for (int i = threadIdx.x; i < HD * HD / 4; i += 256) {
    const int k = i >> 5;
    const int c4 = (i & 31) << 2;
    const float4 v = reinterpret_cast<const float4*>(w1)[i];
    const float vv[4] = {v.x, v.y, v.z, v.w};
#pragma unroll
    for (int q = 0; q < 4; ++q) {
      const int c = c4 + q;
      sWt[c * HD + ((((k >> 3) ^ (c & 15)) << 3) | (k & 7))] = (__bf16)vv[q];
    }
  }
  __syncthreads();

  const float LOG2E2    = 2.88539008177792681f;   // 2*log2(e)
  const float NEG2LOG2E = -2.88539008177792681f;  // -2*log2(e)

  const int lane = threadIdx.x & 63;
  const int wid  = threadIdx.x >> 6;
  const int lr   = lane & 15;
  const int kl   = lane >> 4;

  float w2r[8], b1s[8];
#pragma unroll
  for (int f = 0; f < 8; ++f) {
    w2r[f] = w2[16 * f + lr];
    b1s[f] = LOG2E2 * b1[16 * f + lr];
  }

  // B-fragment LDS byte offsets: addr(hf,kt,fh) = Cb + ((kt^hi2)<<6)
  //   + hf*16384 + fh*4096   (c & 15 == lr for every fragment column).
  const int hi2 = (lr >> 2) & 3;
  int Cb = lr * 256 + ((kl ^ (lr & 3)) << 4);

  const int segStride = gridDim.x * 4;
  for (int b = blockIdx.x * 4 + wid; b < B; b += segStride) {
    const int s0  = seg_start[b];
    const int len = seg_start[b + 1] - s0;
    const int lenm1 = len - 1;
    const int nt  = (len + 15) >> 4;

    float s = 0.f;
    float acc[32], gm[32];
#pragma unroll
    for (int j = 0; j < 32; ++j) { acc[j] = 0.f; gm[j] = -FLT_MAX; }

    if (nt > 0) {
      float hA[32], hB[32];
      LOAD_TILE(hA, 0)
      LOAD_TILE(hB, 1)
      for (int t = 0; t < nt; t += 2) {   // branchless; overruns are no-ops
        PROC_TILE(hA, t)
        LOAD_TILE(hA, t + 2)
        PROC_TILE(hB, t + 1)
        LOAD_TILE(hB, t + 3)
      }
    }

    // Final reduce across the 16 lr lanes, on the VALU (DPP rotate-ops).
#pragma unroll
    for (int st = 1; st <= 8; st <<= 1) {
      if (st == 1) {
        s += dpp_ror<0x121>(s);
#pragma unroll
        for (int j = 0; j < 32; ++j) {
          acc[j] += dpp_ror<0x121>(acc[j]);
          gm[j] = fmaxf(gm[j], dpp_ror<0x121>(gm[j]));
        }
      } else if (st == 2) {
        s += dpp_ror<0x122>(s);
#pragma unroll
        for (int j = 0; j < 32; ++j) {
          acc[j] += dpp_ror<0x122>(acc[j]);
          gm[j] = fmaxf(gm[j], dpp_ror<0x122>(gm[j]));
        }
      } else if (st == 4) {
        s += dpp_ror<0x124>(s);
#pragma unroll
        for (int j = 0; j < 32; ++j) {
          acc[j] += dpp_ror<0x124>(acc[j]);
          gm[j] = fmaxf(gm[j], dpp_ror<0x124>(gm[j]));
        }
      } else {
        s += dpp_ror<0x128>(s);
#pragma unroll
        for (int j = 0; j < 32; ++j) {
          acc[j] += dpp_ror<0x128>(acc[j]);
          gm[j] = fmaxf(gm[j], dpp_ror<0x128>(gm[j]));
        }
      }
    }

    if (lr == 0) {  // lanes 0,16,32,48: one per kl group
      const float invS = (s > 0.f) ? 1.f / s : 0.f;
#pragma unroll
      for (int kt = 0; kt < 4; ++kt) {
        const int fb = 32 * kt + 8 * kl;
        float4 va, vb, ma, mb;
        va.x = acc[8*kt+0]*invS; va.y = acc[8*kt+1]*invS;
        va.z = acc[8*kt+2]*invS; va.w = acc[8*kt+3]*invS;
        vb.x = acc[8*kt+4]*invS; vb.y = acc[8*kt+5]*invS;
        vb.z = acc[8*kt+6]*invS; vb.w = acc[8*kt+7]*invS;
        ma.x = gm[8*kt+0]; ma.y = gm[8*kt+1]; ma.z = gm[8*kt+2]; ma.w = gm[8*kt+3];
        mb.x = gm[8*kt+4]; mb.y = gm[8*kt+5]; mb.z = gm[8*kt+6]; mb.w = gm[8*kt+7];
        *reinterpret_cast<float4*>(&g[(size_t)b * 256 + fb])           = va;
        *reinterpret_cast<float4*>(&g[(size_t)b * 256 + fb + 4])       = vb;
        *reinterpret_cast<float4*>(&g[(size_t)b * 256 + 128 + fb])     = ma;
        *reinterpret_cast<float4*>(&g[(size_t)b * 256 + 128 + fb + 4]) = mb;
      }
    }
  }
}

// -------- Kernel 3: MLP head, 4 segments per block --------
__global__ __launch_bounds__(512) void mlp_kernel(
    const float* __restrict__ g, const float* __restrict__ w1,
    const float* __restrict__ b1, const float* __restrict__ w2,
    const float* __restrict__ b2, float* __restrict__ out)
{
  __shared__ float sg[4][256];
  __shared__ float sred[4][2];
  const int t = threadIdx.x;
  const int sidx = t >> 7;
  const int u = t & 127;
  const int b0 = blockIdx.x * 4;
  sg[sidx][u]       = g[(size_t)(b0 + sidx) * 256 + u];
  sg[sidx][u + 128] = g[(size_t)(b0 + sidx) * 256 + 128 + u];
  __syncthreads();
  float acc = b1[u];
#pragma unroll 8
  for (int k = 0; k < 256; ++k)
    acc = fmaf(sg[sidx][k], w1[k * HD + u], acc);
  float v = fmaxf(acc, 0.f) * w2[u];
#pragma unroll
  for (int off = 32; off >= 1; off >>= 1) v += __shfl_xor(v, off, 64);
  if ((t & 63) == 0) sred[sidx][(t >> 6) & 1] = v;
  __syncthreads();
  if (u == 0) out[b0 + sidx] = sred[sidx][0] + sred[sidx][1] + b2[0];
}

extern "C" void kernel_launch(void* const* d_in, const int* in_sizes, int n_in,
                              void* d_out, int out_size, void* d_ws, size_t ws_size,
                              hipStream_t stream) {
  const float* h       = (const float*)d_in[0];
  const int*   batch   = (const int*)d_in[1];
  const float* gate_w1 = (const float*)d_in[2];
  const float* gate_b1 = (const float*)d_in[3];
  const float* gate_w2 = (const float*)d_in[4];
  const float* mlp_w1  = (const float*)d_in[6];
  const float* mlp_b1  = (const float*)d_in[7];
  const float* mlp_w2  = (const float*)d_in[8];
  const float* mlp_b2  = (const float*)d_in[9];
  float* out = (float*)d_out;

  const int N = in_sizes[0] / HD;   // 1048576
  const int B = out_size;           // 4096

  char* ws = (char*)d_ws;
  float* g   = (float*)ws;                              // B*256 floats
  int*   seg = (int*)(ws + (size_t)B * 256 * 4);        // B+1 ints

  seg_bounds_kernel<<<(B + 256) / 256, 256, 0, stream>>>(batch, N, B, seg);
  // 1024 blocks x 4 waves = 4096 waves -> one segment per wave (static).
  fused_pool_kernel<<<1024, 256, 0, stream>>>(h, gate_w1, gate_b1, gate_w2,
                                              seg, g, B);
  mlp_kernel<<<B / 4, 512, 0, stream>>>(g, mlp_w1, mlp_b1, mlp_w2, mlp_b2, out);
}

// Round 15
// 164.937 us; speedup vs baseline: 1.4183x; 1.0035x over previous
//
#include <hip/hip_runtime.h>
#include <hip/hip_bf16.h>
#include <cfloat>

#define HD 128

typedef float f32x4 __attribute__((ext_vector_type(4)));
typedef __bf16 bf16x8 __attribute__((ext_vector_type(8)));

// -------- Kernel 1: segment bounds (batch is sorted) --------
__global__ void seg_bounds_kernel(const int* __restrict__ batch, int n, int nseg,
                                  int* __restrict__ seg_start) {
  int b = blockIdx.x * blockDim.x + threadIdx.x;
  if (b > nseg) return;
  if (b == nseg) { seg_start[b] = n; return; }
  int lo = 0, hi = n;
  while (lo < hi) {
    int mid = (lo + hi) >> 1;
    if (batch[mid] < b) lo = mid + 1; else hi = mid;
  }
  seg_start[b] = lo;
}

// 16-lane-row rotate (DPP): dst lane i gets lane (i+N) mod 16 within its row.
template <int CTRL>
__device__ __forceinline__ float dpp_ror(float v) {
  return __int_as_float(__builtin_amdgcn_update_dpp(
      0, __float_as_int(v), CTRL, 0xF, 0xF, true));
}

// -------- Kernel 2: FUSED gate-score + FIXED-SHIFT softmax + pooling -------
// EXACT R11 winner (164.5 us): one wave per segment (static, 4096 waves),
// double-buffered h (hA/hB, 64 regs hard budget), branchless 2-deep loop
// (clamped-row overruns are no-ops: w=0), hf-HALVED macc (trans epilogue of
// half 0 overlaps MFMA burst of half 1 — un-halving cost +15us in R13),
// per-kt transient cvt, setprio per half, per-tile DPP reduce.
// Score: score = sumW2 - 2*sum(w2/(1+e^{2x})); consts cancel in softmax,
// |score - const| <= 2*sum|w2| ~ 11 -> fixed shift is fp32-safe.

#define LOAD_TILE(BUF, T)                                                   \
  {                                                                         \
    const int nIt_ = (T) * 16 + lr;                                         \
    const size_t row_ = (size_t)s0 + (size_t)min(nIt_, lenm1);              \
    const float* hp_ = h + row_ * HD + 8 * kl;                              \
    _Pragma("unroll")                                                       \
    for (int kt = 0; kt < 4; ++kt) {                                        \
      *reinterpret_cast<float4*>(&BUF[8 * kt]) =                            \
          *reinterpret_cast<const float4*>(hp_ + 32 * kt);                  \
      *reinterpret_cast<float4*>(&BUF[8 * kt + 4]) =                        \
          *reinterpret_cast<const float4*>(hp_ + 32 * kt + 4);              \
    }                                                                       \
  }

#define PROC_TILE(BUF, T)                                                   \
  {                                                                         \
    const bool valid_ = ((T) * 16 + lr) < len;                              \
    /* opaque: keep B-frag reads inside the loop (anti-LICM) */             \
    asm volatile("" : "+v"(Cb));                                            \
    float p2_[4] = {0.f, 0.f, 0.f, 0.f};                                    \
    _Pragma("unroll")                                                       \
    for (int hf = 0; hf < 2; ++hf) {                                        \
      f32x4 macc_[4];                                                       \
      _Pragma("unroll")                                                     \
      for (int fh = 0; fh < 4; ++fh) macc_[fh] = (f32x4){0.f, 0.f, 0.f, 0.f}; \
      __builtin_amdgcn_s_setprio(1);                                        \
      _Pragma("unroll")                                                     \
      for (int kt = 0; kt < 4; ++kt) {                                      \
        bf16x8 acur_;                                                       \
        _Pragma("unroll")                                                   \
        for (int j = 0; j < 8; ++j) acur_[j] = (__bf16)BUF[8 * kt + j];     \
        const char* bp_ = reinterpret_cast<const char*>(sWt) +              \
                          (Cb + ((kt ^ hi2) << 6)) + hf * 16384;            \
        bf16x8 bfr_[4];                                                     \
        _Pragma("unroll")                                                   \
        for (int fh = 0; fh < 4; ++fh)                                      \
          bfr_[fh] = *reinterpret_cast<const bf16x8*>(bp_ + fh * 4096);     \
        _Pragma("unroll")                                                   \
        for (int fh = 0; fh < 4; ++fh)                                      \
          macc_[fh] = __builtin_amdgcn_mfma_f32_16x16x32_bf16(              \
              acur_, bfr_[fh], macc_[fh], 0, 0, 0);                         \
      }                                                                     \
      __builtin_amdgcn_s_setprio(0);                                        \
      _Pragma("unroll")                                                     \
      for (int fh = 0; fh < 4; ++fh) {                                      \
        const int f_ = 4 * hf + fh;                                         \
        _Pragma("unroll")                                                   \
        for (int r = 0; r < 4; ++r) {                                       \
          const float xe_ = fmaf(LOG2E2, macc_[fh][r], b1s[f_]);            \
          const float e_ = exp2f(xe_);                                      \
          const float t_ = __builtin_amdgcn_rcpf(1.f + e_);                 \
          p2_[r] = fmaf(t_, w2r[f_], p2_[r]);                               \
        }                                                                   \
      }                                                                     \
    }                                                                       \
    /* 16-lane row sum via DPP rotate-adds (1+2+4+8 covers 16) */           \
    _Pragma("unroll")                                                       \
    for (int r = 0; r < 4; ++r) {                                           \
      p2_[r] += dpp_ror<0x121>(p2_[r]);                                     \
      p2_[r] += dpp_ror<0x122>(p2_[r]);                                     \
      p2_[r] += dpp_ror<0x124>(p2_[r]);                                     \
      p2_[r] += dpp_ror<0x128>(p2_[r]);                                     \
    }                                                                       \
    const int rr_ = lr & 3;                                                 \
    const float psel_ =                                                     \
        rr_ == 0 ? p2_[0] : (rr_ == 1 ? p2_[1] : (rr_ == 2 ? p2_[2]         \
                                                            : p2_[3]));     \
    const float sc_ = __shfl(psel_, ((lr >> 2) << 4) | (lr & 3), 64);       \
    const float w_ = valid_ ? exp2f(sc_ * NEG2LOG2E) : 0.f;                 \
    s += w_;                                                                \
    _Pragma("unroll")                                                       \
    for (int j = 0; j < 32; ++j) {                                          \
      acc[j] = fmaf(BUF[j], w_, acc[j]);                                    \
      gm[j] = fmaxf(gm[j], BUF[j]);                                         \
    }                                                                       \
  }

__global__ __launch_bounds__(256, 2) void fused_pool_kernel(
    const float* __restrict__ h, const float* __restrict__ w1,
    const float* __restrict__ b1, const float* __restrict__ w2,
    const int* __restrict__ seg_start, float* __restrict__ g, int B)
{
  __shared__ __bf16 sWt[HD * HD];  // W1^T bf16, XOR-swizzled 16B slots (32 KB)

  for (int i = threadIdx.x; i < HD * HD / 4; i += 256) {
    const int k = i >> 5;
    const int c4 = (i & 31) << 2;
    const float4 v = reinterpret_cast<const float4*>(w1)[i];
    const float vv[4] = {v.x, v.y, v.z, v.w};
#pragma unroll
    for (int q = 0; q < 4; ++q) {
      const int c = c4 + q;
      sWt[c * HD + ((((k >> 3) ^ (c & 15)) << 3) | (k & 7))] = (__bf16)vv[q];
    }
  }
  __syncthreads();

  const float LOG2E2    = 2.88539008177792681f;   // 2*log2(e)
  const float NEG2LOG2E = -2.88539008177792681f;  // -2*log2(e)

  const int lane = threadIdx.x & 63;
  const int wid  = threadIdx.x >> 6;
  const int lr   = lane & 15;
  const int kl   = lane >> 4;

  float w2r[8], b1s[8];
#pragma unroll
  for (int f = 0; f < 8; ++f) {
    w2r[f] = w2[16 * f + lr];
    b1s[f] = LOG2E2 * b1[16 * f + lr];
  }

  // B-fragment LDS byte offsets: addr(hf,kt,fh) = Cb + ((kt^hi2)<<6)
  //   + hf*16384 + fh*4096   (c & 15 == lr for every fragment column).
  const int hi2 = (lr >> 2) & 3;
  int Cb = lr * 256 + ((kl ^ (lr & 3)) << 4);

  const int segStride = gridDim.x * 4;
  for (int b = blockIdx.x * 4 + wid; b < B; b += segStride) {
    const int s0  = seg_start[b];
    const int len = seg_start[b + 1] - s0;
    const int lenm1 = len - 1;
    const int nt  = (len + 15) >> 4;

    float s = 0.f;
    float acc[32], gm[32];
#pragma unroll
    for (int j = 0; j < 32; ++j) { acc[j] = 0.f; gm[j] = -FLT_MAX; }

    if (nt > 0) {
      float hA[32], hB[32];
      LOAD_TILE(hA, 0)
      LOAD_TILE(hB, 1)
      for (int t = 0; t < nt; t += 2) {   // branchless; overruns are no-ops
        PROC_TILE(hA, t)
        LOAD_TILE(hA, t + 2)
        PROC_TILE(hB, t + 1)
        LOAD_TILE(hB, t + 3)
      }
    }

    // Final reduce across the 16 lr lanes, on the VALU (DPP rotate-ops).
#pragma unroll
    for (int st = 1; st <= 8; st <<= 1) {
      if (st == 1) {
        s += dpp_ror<0x121>(s);
#pragma unroll
        for (int j = 0; j < 32; ++j) {
          acc[j] += dpp_ror<0x121>(acc[j]);
          gm[j] = fmaxf(gm[j], dpp_ror<0x121>(gm[j]));
        }
      } else if (st == 2) {
        s += dpp_ror<0x122>(s);
#pragma unroll
        for (int j = 0; j < 32; ++j) {
          acc[j] += dpp_ror<0x122>(acc[j]);
          gm[j] = fmaxf(gm[j], dpp_ror<0x122>(gm[j]));
        }
      } else if (st == 4) {
        s += dpp_ror<0x124>(s);
#pragma unroll
        for (int j = 0; j < 32; ++j) {
          acc[j] += dpp_ror<0x124>(acc[j]);
          gm[j] = fmaxf(gm[j], dpp_ror<0x124>(gm[j]));
        }
      } else {
        s += dpp_ror<0x128>(s);
#pragma unroll
        for (int j = 0; j < 32; ++j) {
          acc[j] += dpp_ror<0x128>(acc[j]);
          gm[j] = fmaxf(gm[j], dpp_ror<0x128>(gm[j]));
        }
      }
    }

    if (lr == 0) {  // lanes 0,16,32,48: one per kl group
      const float invS = (s > 0.f) ? 1.f / s : 0.f;
#pragma unroll
      for (int kt = 0; kt < 4; ++kt) {
        const int fb = 32 * kt + 8 * kl;
        float4 va, vb, ma, mb;
        va.x = acc[8*kt+0]*invS; va.y = acc[8*kt+1]*invS;
        va.z = acc[8*kt+2]*invS; va.w = acc[8*kt+3]*invS;
        vb.x = acc[8*kt+4]*invS; vb.y = acc[8*kt+5]*invS;
        vb.z = acc[8*kt+6]*invS; vb.w = acc[8*kt+7]*invS;
        ma.x = gm[8*kt+0]; ma.y = gm[8*kt+1]; ma.z = gm[8*kt+2]; ma.w = gm[8*kt+3];
        mb.x = gm[8*kt+4]; mb.y = gm[8*kt+5]; mb.z = gm[8*kt+6]; mb.w = gm[8*kt+7];
        *reinterpret_cast<float4*>(&g[(size_t)b * 256 + fb])           = va;
        *reinterpret_cast<float4*>(&g[(size_t)b * 256 + fb + 4])       = vb;
        *reinterpret_cast<float4*>(&g[(size_t)b * 256 + 128 + fb])     = ma;
        *reinterpret_cast<float4*>(&g[(size_t)b * 256 + 128 + fb + 4]) = mb;
      }
    }
  }
}

// -------- Kernel 3: MLP head, 8 segments per 512-thread block --------------
// Each thread owns 2 hidden units (u, u+64) for one of 8 segments; halves
// the per-block mlp_w1 L2 traffic vs the 4-segment version (512 -> 256
// blocks' worth of 128 KB pulls).
__global__ __launch_bounds__(512) void mlp_kernel(
    const float* __restrict__ g, const float* __restrict__ w1,
    const float* __restrict__ b1, const float* __restrict__ w2,
    const float* __restrict__ b2, float* __restrict__ out)
{
  __shared__ float sg[8][256];
  const int t = threadIdx.x;
  const int sidx = t >> 6;        // segment slot 0..7
  const int u = t & 63;           // thread handles hidden units u and u+64
  const int b0 = blockIdx.x * 8;
  // load g: 64 threads per segment x 4 values each
#pragma unroll
  for (int q = 0; q < 4; ++q)
    sg[sidx][u + 64 * q] = g[(size_t)(b0 + sidx) * 256 + u + 64 * q];
  __syncthreads();
  float acc0 = b1[u], acc1 = b1[u + 64];
#pragma unroll 8
  for (int k = 0; k < 256; ++k) {
    const float gv = sg[sidx][k];
    acc0 = fmaf(gv, w1[k * HD + u], acc0);
    acc1 = fmaf(gv, w1[k * HD + u + 64], acc1);
  }
  float v = fmaxf(acc0, 0.f) * w2[u] + fmaxf(acc1, 0.f) * w2[u + 64];
#pragma unroll
  for (int off = 32; off >= 1; off >>= 1) v += __shfl_xor(v, off, 64);
  if (u == 0) out[b0 + sidx] = v + b2[0];
}

extern "C" void kernel_launch(void* const* d_in, const int* in_sizes, int n_in,
                              void* d_out, int out_size, void* d_ws, size_t ws_size,
                              hipStream_t stream) {
  const float* h       = (const float*)d_in[0];
  const int*   batch   = (const int*)d_in[1];
  const float* gate_w1 = (const float*)d_in[2];
  const float* gate_b1 = (const float*)d_in[3];
  const float* gate_w2 = (const float*)d_in[4];
  const float* mlp_w1  = (const float*)d_in[6];
  const float* mlp_b1  = (const float*)d_in[7];
  const float* mlp_w2  = (const float*)d_in[8];
  const float* mlp_b2  = (const float*)d_in[9];
  float* out = (float*)d_out;

  const int N = in_sizes[0] / HD;   // 1048576
  const int B = out_size;           // 4096

  char* ws = (char*)d_ws;
  float* g   = (float*)ws;                              // B*256 floats
  int*   seg = (int*)(ws + (size_t)B * 256 * 4);        // B+1 ints

  seg_bounds_kernel<<<(B + 256) / 256, 256, 0, stream>>>(batch, N, B, seg);
  // 1024 blocks x 4 waves = 4096 waves -> one segment per wave (static).
  fused_pool_kernel<<<1024, 256, 0, stream>>>(h, gate_w1, gate_b1, gate_w2,
                                              seg, g, B);
  mlp_kernel<<<B / 8, 512, 0, stream>>>(g, mlp_w1, mlp_b1, mlp_w2, mlp_b2, out);
}

// Round 16
// 157.974 us; speedup vs baseline: 1.4808x; 1.0441x over previous
//
#include <hip/hip_runtime.h>
#include <hip/hip_bf16.h>
#include <cfloat>

#define HD 128

typedef float f32x4 __attribute__((ext_vector_type(4)));
typedef __bf16 bf16x8 __attribute__((ext_vector_type(8)));

// -------- Kernel 1: segment bounds (batch is sorted) --------
__global__ void seg_bounds_kernel(const int* __restrict__ batch, int n, int nseg,
                                  int* __restrict__ seg_start) {
  int b = blockIdx.x * blockDim.x + threadIdx.x;
  if (b > nseg) return;
  if (b == nseg) { seg_start[b] = n; return; }
  int lo = 0, hi = n;
  while (lo < hi) {
    int mid = (lo + hi) >> 1;
    if (batch[mid] < b) lo = mid + 1; else hi = mid;
  }
  seg_start[b] = lo;
}

// 16-lane-row rotate (DPP): dst lane i gets lane (i+N) mod 16 within its row.
template <int CTRL>
__device__ __forceinline__ float dpp_ror(float v) {
  return __int_as_float(__builtin_amdgcn_update_dpp(
      0, __float_as_int(v), CTRL, 0xF, 0xF, true));
}

// -------- Kernel 2: FULLY-FUSED gate-score + softmax + pooling + MLP -------
// Hot loop = EXACT R11/R15 winner (164.5 us): one wave per segment (static,
// 4096 waves), double-buffered h (hA/hB), branchless 2-deep loop (clamped
// rows; overrun PROCs are no-ops, w=0), hf-HALVED macc (trans epilogue of
// half 0 overlaps MFMA burst of half 1), per-kt transient cvt, setprio per
// half, per-tile DPP reduce.
// NEW: per-segment MLP tail. The wave writes its (g_attn|g_max) into a
// per-wave 1KB LDS slot (wave-internal, lgkmcnt-ordered, no barrier), then
// computes out[b] = w2m . relu(W1m.g + b1m) + b2m itself: 64 lanes x 2
// hidden units, coalesced w1m dword streams (L2-resident). Deletes the
// separate mlp kernel + the 8MB g round-trip.
// Score: score = sumW2 - 2*sum(w2/(1+e^{2x})); consts cancel in softmax,
// |score - const| <= 2*sum|w2| ~ 11 -> fixed shift is fp32-safe.

#define LOAD_TILE(BUF, T)                                                   \
  {                                                                         \
    const int nIt_ = (T) * 16 + lr;                                         \
    const size_t row_ = (size_t)s0 + (size_t)min(nIt_, lenm1);              \
    const float* hp_ = h + row_ * HD + 8 * kl;                              \
    _Pragma("unroll")                                                       \
    for (int kt = 0; kt < 4; ++kt) {                                        \
      *reinterpret_cast<float4*>(&BUF[8 * kt]) =                            \
          *reinterpret_cast<const float4*>(hp_ + 32 * kt);                  \
      *reinterpret_cast<float4*>(&BUF[8 * kt + 4]) =                        \
          *reinterpret_cast<const float4*>(hp_ + 32 * kt + 4);              \
    }                                                                       \
  }

#define PROC_TILE(BUF, T)                                                   \
  {                                                                         \
    const bool valid_ = ((T) * 16 + lr) < len;                              \
    /* opaque: keep B-frag reads inside the loop (anti-LICM) */             \
    asm volatile("" : "+v"(Cb));                                            \
    float p2_[4] = {0.f, 0.f, 0.f, 0.f};                                    \
    _Pragma("unroll")                                                       \
    for (int hf = 0; hf < 2; ++hf) {                                        \
      f32x4 macc_[4];                                                       \
      _Pragma("unroll")                                                     \
      for (int fh = 0; fh < 4; ++fh) macc_[fh] = (f32x4){0.f, 0.f, 0.f, 0.f}; \
      __builtin_amdgcn_s_setprio(1);                                        \
      _Pragma("unroll")                                                     \
      for (int kt = 0; kt < 4; ++kt) {                                      \
        bf16x8 acur_;                                                       \
        _Pragma("unroll")                                                   \
        for (int j = 0; j < 8; ++j) acur_[j] = (__bf16)BUF[8 * kt + j];     \
        const char* bp_ = reinterpret_cast<const char*>(sWt) +              \
                          (Cb + ((kt ^ hi2) << 6)) + hf * 16384;            \
        bf16x8 bfr_[4];                                                     \
        _Pragma("unroll")                                                   \
        for (int fh = 0; fh < 4; ++fh)                                      \
          bfr_[fh] = *reinterpret_cast<const bf16x8*>(bp_ + fh * 4096);     \
        _Pragma("unroll")                                                   \
        for (int fh = 0; fh < 4; ++fh)                                      \
          macc_[fh] = __builtin_amdgcn_mfma_f32_16x16x32_bf16(              \
              acur_, bfr_[fh], macc_[fh], 0, 0, 0);                         \
      }                                                                     \
      __builtin_amdgcn_s_setprio(0);                                        \
      _Pragma("unroll")                                                     \
      for (int fh = 0; fh < 4; ++fh) {                                      \
        const int f_ = 4 * hf + fh;                                         \
        _Pragma("unroll")                                                   \
        for (int r = 0; r < 4; ++r) {                                       \
          const float xe_ = fmaf(LOG2E2, macc_[fh][r], b1s[f_]);            \
          const float e_ = exp2f(xe_);                                      \
          const float t_ = __builtin_amdgcn_rcpf(1.f + e_);                 \
          p2_[r] = fmaf(t_, w2r[f_], p2_[r]);                               \
        }                                                                   \
      }                                                                     \
    }                                                                       \
    /* 16-lane row sum via DPP rotate-adds (1+2+4+8 covers 16) */           \
    _Pragma("unroll")                                                       \
    for (int r = 0; r < 4; ++r) {                                           \
      p2_[r] += dpp_ror<0x121>(p2_[r]);                                     \
      p2_[r] += dpp_ror<0x122>(p2_[r]);                                     \
      p2_[r] += dpp_ror<0x124>(p2_[r]);                                     \
      p2_[r] += dpp_ror<0x128>(p2_[r]);                                     \
    }                                                                       \
    const int rr_ = lr & 3;                                                 \
    const float psel_ =                                                     \
        rr_ == 0 ? p2_[0] : (rr_ == 1 ? p2_[1] : (rr_ == 2 ? p2_[2]         \
                                                            : p2_[3]));     \
    const float sc_ = __shfl(psel_, ((lr >> 2) << 4) | (lr & 3), 64);       \
    const float w_ = valid_ ? exp2f(sc_ * NEG2LOG2E) : 0.f;                 \
    s += w_;                                                                \
    _Pragma("unroll")                                                       \
    for (int j = 0; j < 32; ++j) {                                          \
      acc[j] = fmaf(BUF[j], w_, acc[j]);                                    \
      gm[j] = fmaxf(gm[j], BUF[j]);                                         \
    }                                                                       \
  }

__global__ __launch_bounds__(256, 2) void fused_pool_kernel(
    const float* __restrict__ h, const float* __restrict__ w1,
    const float* __restrict__ b1, const float* __restrict__ w2,
    const int* __restrict__ seg_start, int B,
    const float* __restrict__ w1m, const float* __restrict__ b1m,
    const float* __restrict__ w2m, const float* __restrict__ b2m,
    float* __restrict__ out)
{
  __shared__ __bf16 sWt[HD * HD];  // W1^T bf16, XOR-swizzled 16B slots (32 KB)
  __shared__ float sG[4][256];     // per-wave g slot: [0..128)=attn,[128..)=max

  for (int i = threadIdx.x; i < HD * HD / 4; i += 256) {
    const int k = i >> 5;
    const int c4 = (i & 31) << 2;
    const float4 v = reinterpret_cast<const float4*>(w1)[i];
    const float vv[4] = {v.x, v.y, v.z, v.w};
#pragma unroll
    for (int q = 0; q < 4; ++q) {
      const int c = c4 + q;
      sWt[c * HD + ((((k >> 3) ^ (c & 15)) << 3) | (k & 7))] = (__bf16)vv[q];
    }
  }
  __syncthreads();

  const float LOG2E2    = 2.88539008177792681f;   // 2*log2(e)
  const float NEG2LOG2E = -2.88539008177792681f;  // -2*log2(e)

  const int lane = threadIdx.x & 63;
  const int wid  = threadIdx.x >> 6;
  const int lr   = lane & 15;
  const int kl   = lane >> 4;

  float w2r[8], b1s[8];
#pragma unroll
  for (int f = 0; f < 8; ++f) {
    w2r[f] = w2[16 * f + lr];
    b1s[f] = LOG2E2 * b1[16 * f + lr];
  }

  // B-fragment LDS byte offsets: addr(hf,kt,fh) = Cb + ((kt^hi2)<<6)
  //   + hf*16384 + fh*4096   (c & 15 == lr for every fragment column).
  const int hi2 = (lr >> 2) & 3;
  int Cb = lr * 256 + ((kl ^ (lr & 3)) << 4);

  const int segStride = gridDim.x * 4;
  for (int b = blockIdx.x * 4 + wid; b < B; b += segStride) {
    const int s0  = seg_start[b];
    const int len = seg_start[b + 1] - s0;
    const int lenm1 = len - 1;
    const int nt  = (len + 15) >> 4;

    float s = 0.f;
    float acc[32], gm[32];
#pragma unroll
    for (int j = 0; j < 32; ++j) { acc[j] = 0.f; gm[j] = -FLT_MAX; }

    if (nt > 0) {
      float hA[32], hB[32];
      LOAD_TILE(hA, 0)
      LOAD_TILE(hB, 1)
      for (int t = 0; t < nt; t += 2) {   // branchless; overruns are no-ops
        PROC_TILE(hA, t)
        LOAD_TILE(hA, t + 2)
        PROC_TILE(hB, t + 1)
        LOAD_TILE(hB, t + 3)
      }
    }

    // Final reduce across the 16 lr lanes, on the VALU (DPP rotate-ops).
#pragma unroll
    for (int st = 1; st <= 8; st <<= 1) {
      if (st == 1) {
        s += dpp_ror<0x121>(s);
#pragma unroll
        for (int j = 0; j < 32; ++j) {
          acc[j] += dpp_ror<0x121>(acc[j]);
          gm[j] = fmaxf(gm[j], dpp_ror<0x121>(gm[j]));
        }
      } else if (st == 2) {
        s += dpp_ror<0x122>(s);
#pragma unroll
        for (int j = 0; j < 32; ++j) {
          acc[j] += dpp_ror<0x122>(acc[j]);
          gm[j] = fmaxf(gm[j], dpp_ror<0x122>(gm[j]));
        }
      } else if (st == 4) {
        s += dpp_ror<0x124>(s);
#pragma unroll
        for (int j = 0; j < 32; ++j) {
          acc[j] += dpp_ror<0x124>(acc[j]);
          gm[j] = fmaxf(gm[j], dpp_ror<0x124>(gm[j]));
        }
      } else {
        s += dpp_ror<0x128>(s);
#pragma unroll
        for (int j = 0; j < 32; ++j) {
          acc[j] += dpp_ror<0x128>(acc[j]);
          gm[j] = fmaxf(gm[j], dpp_ror<0x128>(gm[j]));
        }
      }
    }

    // Stage g into this wave's LDS slot (wave-internal, lgkmcnt-ordered).
    if (lr == 0) {  // lanes 0,16,32,48: one per kl group
      const float invS = (s > 0.f) ? 1.f / s : 0.f;
#pragma unroll
      for (int kt = 0; kt < 4; ++kt) {
        const int fb = 32 * kt + 8 * kl;
        float4 va, vb, ma, mb;
        va.x = acc[8*kt+0]*invS; va.y = acc[8*kt+1]*invS;
        va.z = acc[8*kt+2]*invS; va.w = acc[8*kt+3]*invS;
        vb.x = acc[8*kt+4]*invS; vb.y = acc[8*kt+5]*invS;
        vb.z = acc[8*kt+6]*invS; vb.w = acc[8*kt+7]*invS;
        ma.x = gm[8*kt+0]; ma.y = gm[8*kt+1]; ma.z = gm[8*kt+2]; ma.w = gm[8*kt+3];
        mb.x = gm[8*kt+4]; mb.y = gm[8*kt+5]; mb.z = gm[8*kt+6]; mb.w = gm[8*kt+7];
        *reinterpret_cast<float4*>(&sG[wid][fb])           = va;
        *reinterpret_cast<float4*>(&sG[wid][fb + 4])       = vb;
        *reinterpret_cast<float4*>(&sG[wid][128 + fb])     = ma;
        *reinterpret_cast<float4*>(&sG[wid][128 + fb + 4]) = mb;
      }
    }
    asm volatile("s_waitcnt lgkmcnt(0)" ::: "memory");  // wave-internal flush

    // ---- MLP tail: 64 lanes x 2 hidden units; coalesced w1m streams ----
    {
      const int u = lane;
      float a0 = b1m[u], a1 = b1m[u + 64];
      const float* wp0 = w1m + u;
#pragma unroll 8
      for (int kq = 0; kq < 64; ++kq) {
        const float4 g4 = *reinterpret_cast<const float4*>(&sG[wid][4 * kq]);
        const float* wk = wp0 + (size_t)(4 * kq) * HD;
        a0 = fmaf(g4.x, wk[0],            a0);
        a1 = fmaf(g4.x, wk[64],           a1);
        a0 = fmaf(g4.y, wk[HD],           a0);
        a1 = fmaf(g4.y, wk[HD + 64],      a1);
        a0 = fmaf(g4.z, wk[2 * HD],       a0);
        a1 = fmaf(g4.z, wk[2 * HD + 64],  a1);
        a0 = fmaf(g4.w, wk[3 * HD],       a0);
        a1 = fmaf(g4.w, wk[3 * HD + 64],  a1);
      }
      float v = fmaxf(a0, 0.f) * w2m[u] + fmaxf(a1, 0.f) * w2m[u + 64];
#pragma unroll
      for (int off = 32; off >= 1; off >>= 1) v += __shfl_xor(v, off, 64);
      if (lane == 0) out[b] = v + b2m[0];
    }
  }
}

extern "C" void kernel_launch(void* const* d_in, const int* in_sizes, int n_in,
                              void* d_out, int out_size, void* d_ws, size_t ws_size,
                              hipStream_t stream) {
  const float* h       = (const float*)d_in[0];
  const int*   batch   = (const int*)d_in[1];
  const float* gate_w1 = (const float*)d_in[2];
  const float* gate_b1 = (const float*)d_in[3];
  const float* gate_w2 = (const float*)d_in[4];
  const float* mlp_w1  = (const float*)d_in[6];
  const float* mlp_b1  = (const float*)d_in[7];
  const float* mlp_w2  = (const float*)d_in[8];
  const float* mlp_b2  = (const float*)d_in[9];
  float* out = (float*)d_out;

  const int N = in_sizes[0] / HD;   // 1048576
  const int B = out_size;           // 4096

  int* seg = (int*)d_ws;            // B+1 ints

  seg_bounds_kernel<<<(B + 256) / 256, 256, 0, stream>>>(batch, N, B, seg);
  // 1024 blocks x 4 waves = 4096 waves -> one segment per wave (static).
  fused_pool_kernel<<<1024, 256, 0, stream>>>(h, gate_w1, gate_b1, gate_w2,
                                              seg, B, mlp_w1, mlp_b1, mlp_w2,
                                              mlp_b2, out);
}